// Round 1
// baseline (353.766 us; speedup 1.0000x reference)
//
#include <hip/hip_runtime.h>
#include <hip/hip_cooperative_groups.h>

namespace cg = cooperative_groups;

// out[w] = -sum_{n,h} log( x[n, q(n,h,w), h, w] )
// q = clamp(floor((y[n,0,h,w]+110)/10),0,20)*21 + clamp(floor((y[n,1,h,w]+110)/10),0,20)
//
// Shapes: x [8,441,128,128] f32, y [8,2,128,128] f32, out [128] f32.
//
// Fused single cooperative kernel:
//   Phase 1: 1024 blocks (one per (n,h) row) x 128 threads (lane = w).
//            y loads coalesced; x gather scattered (inherent); per-(row,w)
//            log values written coalesced to ws [1024 x 128].
//   grid.sync()
//   Phase 2: blocks 0..127 each reduce one w column (1024 partials,
//            L2/L3-resident, 512 KB total), write out[w] = -total.
//
// Rationale: removes the second kernel dispatch + its launch/drain overhead.
// This is also a null-test: rocprof shows the timed region is dominated by
// the harness's ~882MB poison fills (~140us @ 80% HBM peak); our kernels are
// ~10-20us by roofline arithmetic. If dur_us doesn't move, we are at the
// harness floor.

#define N_ 8
#define H_ 128
#define W_ 128
#define Q_ 441
#define NROWS (N_ * H_)   // 1024

__global__ __launch_bounds__(128) void mce_fused_kernel(
    const float* __restrict__ x, const float* __restrict__ y,
    float* __restrict__ out, float* __restrict__ ws) {
    const int row = blockIdx.x;     // 0..1023 == n*128 + h
    const int w   = threadIdx.x;    // 0..127  (lane dim -> coalesced)
    const int n = row >> 7;
    const int h = row & 127;

    // ---- Phase 1: gather + log, write partials ----
    // y[n, c, h, w]: contiguous in w -> coalesced 512B row reads
    const int ybase = ((n * 2) * H_ + h) * W_ + w;
    const float ya = y[ybase];
    const float yb = y[ybase + H_ * W_];

    // match reference exactly: floor((y + 110)/10), clamp [0,20]
    int qa = (int)floorf((ya + 110.0f) / 10.0f);
    int qb = (int)floorf((yb + 110.0f) / 10.0f);
    qa = min(max(qa, 0), 20);
    qb = min(max(qb, 0), 20);
    const int q = qa * 21 + qb;

    // x[n, q, h, w] — scattered gather (q random per lane)
    const size_t xoff = (((size_t)n * Q_ + q) * H_ + h) * W_ + w;
    ws[row * W_ + w] = logf(x[xoff]);

    // ---- grid-wide barrier (includes device-scope memory ordering) ----
    cg::this_grid().sync();

    // ---- Phase 2: blocks 0..127 reduce one w column each ----
    if (row < W_) {
        const int wo = row;        // output column this block owns
        const int t  = w;          // 0..127

        float acc = 0.0f;
        #pragma unroll
        for (int k = 0; k < NROWS / 128; ++k)       // 8 rows per thread
            acc += ws[(t + k * 128) * W_ + wo];

        // wave-64 shuffle reduction over 2 waves
        #pragma unroll
        for (int off = 32; off > 0; off >>= 1)
            acc += __shfl_down(acc, off, 64);

        __shared__ float smem[2];
        if ((t & 63) == 0) smem[t >> 6] = acc;
        __syncthreads();

        if (t == 0)
            out[wo] = -(smem[0] + smem[1]);
    }
}

extern "C" void kernel_launch(void* const* d_in, const int* in_sizes, int n_in,
                              void* d_out, int out_size, void* d_ws, size_t ws_size,
                              hipStream_t stream) {
    const float* x = (const float*)d_in[0];
    const float* y = (const float*)d_in[1];
    float* out = (float*)d_out;
    float* ws  = (float*)d_ws;   // needs 1024*128*4 = 512 KB

    void* args[] = { (void*)&x, (void*)&y, (void*)&out, (void*)&ws };
    hipLaunchCooperativeKernel((const void*)mce_fused_kernel,
                               dim3(NROWS), dim3(128), args, 0, stream);
}

// Round 2
// 262.292 us; speedup vs baseline: 1.3488x; 1.3488x over previous
//
#include <hip/hip_runtime.h>
#include <hip/hip_bf16.h>

// out[w] = -sum_{n,h} log( x[n, q(n,h,w), h, w] )
// q = clamp(floor((y[n,0,h,w]+110)/10),0,20)*21 + clamp(floor((y[n,1,h,w]+110)/10),0,20)
//
// Shapes: x [8,441,128,128] f32, y [8,2,128,128] f32, out [128] f32.
//
// Two-pass deterministic reduction (REVERT of the cooperative-launch fusion:
// hipLaunchCooperativeKernel in the captured timed region cost +91us):
//   Kernel A: 1024 blocks (one per (n,h) row) x 128 threads (lane = w).
//             y loads coalesced; x gather scattered (inherent); partial
//             per-(row,w) log values written coalesced to d_ws [1024 x 128].
//   Kernel B: 128 blocks (one per w) x 256 threads; sums the 1024 partials
//             for its w (L2/L3-resident, 512 KB total), writes out[w] = -total.
//
// Roofline note: rocprof shows the timed region is dominated by harness
// re-poison fills (~882 MB at 81-83% of HBM peak, ~140us each). Our two
// dispatches total ~10-20us (9 MB gather + 1 MB y + 0.5 MB ws + L3 reduce)
// and do not appear in the top-5 dispatches.

#define N_ 8
#define H_ 128
#define W_ 128
#define Q_ 441
#define NROWS (N_ * H_)   // 1024

__global__ __launch_bounds__(128) void mce_partial_kernel(
    const float* __restrict__ x, const float* __restrict__ y,
    float* __restrict__ ws) {
    const int row = blockIdx.x;     // 0..1023 == n*128 + h
    const int w   = threadIdx.x;    // 0..127  (lane dim -> coalesced)
    const int n = row >> 7;
    const int h = row & 127;

    // y[n, c, h, w]: contiguous in w -> coalesced 512B row reads
    const int ybase = ((n * 2) * H_ + h) * W_ + w;
    const float ya = y[ybase];
    const float yb = y[ybase + H_ * W_];

    // match reference exactly: floor((y + 110)/10), clamp [0,20]
    int qa = (int)floorf((ya + 110.0f) / 10.0f);
    int qb = (int)floorf((yb + 110.0f) / 10.0f);
    qa = min(max(qa, 0), 20);
    qb = min(max(qb, 0), 20);
    const int q = qa * 21 + qb;

    // x[n, q, h, w] — scattered gather (q random per lane)
    const size_t xoff = (((size_t)n * Q_ + q) * H_ + h) * W_ + w;
    ws[row * W_ + w] = logf(x[xoff]);
}

__global__ __launch_bounds__(256) void mce_reduce_kernel(
    const float* __restrict__ ws, float* __restrict__ out) {
    const int w = blockIdx.x;   // 0..127
    const int t = threadIdx.x;  // 0..255

    // each thread sums 4 of the 1024 row-partials for this w
    float acc = 0.0f;
    #pragma unroll
    for (int k = 0; k < NROWS / 256; ++k)
        acc += ws[(t + k * 256) * W_ + w];

    // wave-64 shuffle reduction
    #pragma unroll
    for (int off = 32; off > 0; off >>= 1)
        acc += __shfl_down(acc, off, 64);

    __shared__ float smem[4];
    const int wave = t >> 6;
    const int lane = t & 63;
    if (lane == 0) smem[wave] = acc;
    __syncthreads();

    if (t == 0)
        out[w] = -(smem[0] + smem[1] + smem[2] + smem[3]);
}

extern "C" void kernel_launch(void* const* d_in, const int* in_sizes, int n_in,
                              void* d_out, int out_size, void* d_ws, size_t ws_size,
                              hipStream_t stream) {
    const float* x = (const float*)d_in[0];
    const float* y = (const float*)d_in[1];
    float* out = (float*)d_out;
    float* ws  = (float*)d_ws;   // needs 1024*128*4 = 512 KB

    mce_partial_kernel<<<NROWS, 128, 0, stream>>>(x, y, ws);
    mce_reduce_kernel<<<W_, 256, 0, stream>>>(ws, out);
}